// Round 22
// baseline (59.803 us; speedup 1.0000x reference)
//
#include <hip/hip_runtime.h>
#include <hip/hip_bf16.h>
#include <stdint.h>

#define SEQ     4096
#define HIDDEN  640
#define HDIM    80
#define NH      8
#define NKV     2
#define WINDOW  512
#define SINK    4
#define BQG     32    // flash q-tile (shared by 4 heads)
#define BK      128   // flash key-tile
#define KSTR    104   // Ks row stride (bf16): 2-way banks on b128 reads
#define VSTR    136   // Vt/Pl row stride (bf16): 2-way banks (128+8)
#define VSTRK   40    // Vtk sink row stride

typedef __bf16 bf16x8 __attribute__((ext_vector_type(8)));
typedef __bf16 bf16x4 __attribute__((ext_vector_type(4)));
typedef float  f32x4  __attribute__((ext_vector_type(4)));

__device__ inline __bf16 f2bf(float f) {
    union { float f; uint32_t u; } x; x.f = f;
    uint32_t r = x.u + 0x7FFF + ((x.u >> 16) & 1);   // RNE, no NaN inputs
    union { unsigned short s; __bf16 b; } y; y.s = (unsigned short)(r >> 16);
    return y.b;
}
__device__ inline float bf2f(unsigned short u) {
    union { uint32_t u; float f; } c; c.u = ((uint32_t)u) << 16; return c.f;
}
__device__ inline float fexp2(float x) {
#if __has_builtin(__builtin_amdgcn_exp2f)
    return __builtin_amdgcn_exp2f(x);
#else
    return exp2f(x);
#endif
}

// ---------------------------------------------------------------------------
// Fused prep: x -> bf16 (blocks [0,2560)) + all weight transposes
// (blocks [2560,3560), 32x32 tiles).  (r12-proven)
// ---------------------------------------------------------------------------
__global__ __launch_bounds__(256) void prep_kernel(
    const float* __restrict__ x, const float* __restrict__ Wq,
    const float* __restrict__ Wk, const float* __restrict__ Wv,
    const float* __restrict__ Wo, __bf16* __restrict__ xb,
    __bf16* __restrict__ WqkvT, __bf16* __restrict__ WoT)
{
    const int flat = blockIdx.x;
    const int tid  = threadIdx.x;
    if (flat < 2560) {
        int i = flat * 256 + tid;
        const float4 v = *(const float4*)&x[4 * i];
        xb[4 * i + 0] = f2bf(v.x);
        xb[4 * i + 1] = f2bf(v.y);
        xb[4 * i + 2] = f2bf(v.z);
        xb[4 * i + 3] = f2bf(v.w);
        return;
    }
    const int wf = flat - 2560;
    const float* src;
    __bf16* dstb;
    int idx, tiles_x, N;
    if (wf < 400)      { src = Wq; dstb = WqkvT;             idx = wf;       tiles_x = 20; N = 640; }
    else if (wf < 500) { src = Wk; dstb = WqkvT + 640 * 640; idx = wf - 400; tiles_x = 5;  N = 160; }
    else if (wf < 600) { src = Wv; dstb = WqkvT + 800 * 640; idx = wf - 500; tiles_x = 5;  N = 160; }
    else               { src = Wo; dstb = WoT;               idx = wf - 600; tiles_x = 20; N = 640; }
    const int n0 = (idx % tiles_x) * 32;
    const int k0 = (idx / tiles_x) * 32;

    __shared__ float t[32][33];
    const int tx = tid & 31, ty = tid >> 5;     // 32 x 8
    #pragma unroll
    for (int i = 0; i < 4; ++i) {
        int r = ty + 8 * i;
        t[r][tx] = src[(size_t)(k0 + r) * N + n0 + tx];
    }
    __syncthreads();
    #pragma unroll
    for (int i = 0; i < 4; ++i) {
        int r = ty + 8 * i;
        dstb[(size_t)(n0 + r) * 640 + k0 + tx] = f2bf(t[tx][r]);
    }
}

// ---------------------------------------------------------------------------
// FUSED QKV GEMM + RMSNorm + RoPE + V-transpose. Tile 64x160 (head-aligned:
// each column block = 2 whole heads), grid (M/64, 6). Based on the r20-proven
// n160 structure (8 waves = 4M x 2N, wave tile 16x80, acc[5], BK=64 dbuf).
// Epilogue per block:
//   y<4 : q-heads 2y,2y+1 -> rmsnorm (in-wave shfl reduce) + rope -> qb
//   y==4: k-heads 8,9     -> rmsnorm + rope -> kb
//   y==5: V               -> write vtb[kvh][d][seq] transposed
// Key fact: for a fixed row, one wave holds the row's whole 80-col head
// (16 l15-lanes x 5 frags) -> norm reduce = 4 shfl_xor; rope partner =
// shfl_xor(.,1). Norm on fp32 acc (closer to fp32 reference than panel).
// ---------------------------------------------------------------------------
__global__ __launch_bounds__(512) void gemm_qkv_fused(
    const __bf16* __restrict__ A, const __bf16* __restrict__ BT,
    const float* __restrict__ cosb, const float* __restrict__ sinb,
    const float* __restrict__ qw, const float* __restrict__ kw,
    __bf16* __restrict__ qb, __bf16* __restrict__ kb,
    __bf16* __restrict__ vtb, int M, int K)
{
    __shared__ __bf16 As[2][2][64][40];    // 20480 B
    __shared__ __bf16 Bs[2][2][160][40];   // 51200 B
    const int BUFA = 64 * 40;
    const int BUFB = 160 * 40;

    const int tid  = threadIdx.x;
    const int wave = tid >> 6;
    const int lane = tid & 63;
    const int wr = wave >> 1, wc = wave & 1;     // 4M x 2N
    const int l15 = lane & 15, lq = lane >> 4;
    const int m0 = blockIdx.x * 64, bn = blockIdx.y, n0 = bn * 160;

    f32x4 acc[5];
    #pragma unroll
    for (int n = 0; n < 5; ++n) acc[n] = (f32x4)0.0f;

    size_t goff[4];
    __bf16* ldst[4];
    int     bstr[4];
    const bool act3 = (tid < 256);
    {
        int r0 = tid >> 3, q0 = tid & 7, h0 = q0 >> 2, s0 = q0 & 3;
        goff[0] = (size_t)(m0 + r0) * K + h0 * 32 + 8 * s0;
        ldst[0] = &As[h0][0][r0][8 * s0];
        bstr[0] = BUFA;
        #pragma unroll
        for (int j = 1; j < 4; ++j) {
            int b  = tid + (j - 1) * 512;
            if (j == 3 && !act3) b = 0;
            int rb = b >> 3, qb_ = b & 7, hb = qb_ >> 2, sb = qb_ & 3;
            goff[j] = (size_t)(n0 + rb) * K + hb * 32 + 8 * sb;
            ldst[j] = &Bs[hb][0][rb][8 * sb];
            bstr[j] = BUFB;
        }
    }
    const __bf16* gsrcs[4] = { A, BT, BT, BT };

    const int nk = K >> 6;

    bf16x8 rg0 = *(const bf16x8*)&gsrcs[0][goff[0]];
    bf16x8 rg1 = *(const bf16x8*)&gsrcs[1][goff[1]];
    bf16x8 rg2 = *(const bf16x8*)&gsrcs[2][goff[2]];
    bf16x8 rg3;
    if (act3) rg3 = *(const bf16x8*)&gsrcs[3][goff[3]];
    *(bf16x8*)ldst[0] = rg0;
    *(bf16x8*)ldst[1] = rg1;
    *(bf16x8*)ldst[2] = rg2;
    if (act3) *(bf16x8*)ldst[3] = rg3;
    __syncthreads();

    for (int ks = 0; ks < nk; ++ks) {
        const int cur = ks & 1;
        if (ks + 1 < nk) {
            const size_t kadv = (size_t)(ks + 1) * 64;
            rg0 = *(const bf16x8*)&gsrcs[0][goff[0] + kadv];
            rg1 = *(const bf16x8*)&gsrcs[1][goff[1] + kadv];
            rg2 = *(const bf16x8*)&gsrcs[2][goff[2] + kadv];
            if (act3) rg3 = *(const bf16x8*)&gsrcs[3][goff[3] + kadv];
        }

        __builtin_amdgcn_s_setprio(1);
        #pragma unroll
        for (int h = 0; h < 2; ++h) {
            bf16x8 af = *(const bf16x8*)&As[h][cur][wr * 16 + l15][8 * lq];
            #pragma unroll
            for (int n = 0; n < 5; ++n) {
                bf16x8 bfr = *(const bf16x8*)&Bs[h][cur][wc * 80 + n * 16 + l15][8 * lq];
                acc[n] = __builtin_amdgcn_mfma_f32_16x16x32_bf16(af, bfr, acc[n], 0, 0, 0);
            }
        }
        __builtin_amdgcn_s_setprio(0);

        if (ks + 1 < nk) {
            *(bf16x8*)(ldst[0] + (cur ^ 1) * bstr[0]) = rg0;
            *(bf16x8*)(ldst[1] + (cur ^ 1) * bstr[1]) = rg1;
            *(bf16x8*)(ldst[2] + (cur ^ 1) * bstr[2]) = rg2;
            if (act3) *(bf16x8*)(ldst[3] + (cur ^ 1) * bstr[3]) = rg3;
        }
        __syncthreads();
    }

    // ---- fused epilogue ----
    if (bn == 5) {
        // V block: write vtb[kvh*80+d][seq] = vtb[dg][row] transposed
        #pragma unroll
        for (int n = 0; n < 5; ++n) {
            const int dg = wc * 80 + n * 16 + l15;       // 0..159
            #pragma unroll
            for (int r = 0; r < 4; ++r) {
                const int row = m0 + wr * 16 + 4 * lq + r;
                vtb[(size_t)dg * SEQ + row] = f2bf(acc[n][r]);
            }
        }
        return;
    }

    const bool  isq = (bn < 4);
    const int   head = 2 * bn + wc;                      // q: 0..7 ; k: 8,9
    const float outscale = isq ? (0.11180339887498948f * 1.4426950408889634f) : 1.0f;
    const float* wsrc = isq ? qw : kw;
    float wv[5];
    #pragma unroll
    for (int n = 0; n < 5; ++n) wv[n] = wsrc[16 * n + l15];
    const float sgn = (l15 & 1) ? 1.0f : -1.0f;

    #pragma unroll
    for (int r = 0; r < 4; ++r) {
        const int row = m0 + wr * 16 + 4 * lq + r;
        float ss = 0.0f;
        #pragma unroll
        for (int n = 0; n < 5; ++n) ss += acc[n][r] * acc[n][r];
        ss += __shfl_xor(ss, 1);
        ss += __shfl_xor(ss, 2);
        ss += __shfl_xor(ss, 4);
        ss += __shfl_xor(ss, 8);
        const float rms = rsqrtf(ss * (1.0f / HDIM) + 1e-5f);

        #pragma unroll
        for (int n = 0; n < 5; ++n) {
            float v = acc[n][r] * rms * wv[n];
            float p = __shfl_xor(v, 1);
            float c = cosb[(size_t)row * 40 + 8 * n + (l15 >> 1)];
            float s = sinb[(size_t)row * 40 + 8 * n + (l15 >> 1)];
            float outv = (v * c + sgn * p * s) * outscale;
            if (isq)
                qb[(size_t)row * HIDDEN + head * HDIM + 16 * n + l15] = (__bf16)outv;
            else
                kb[(size_t)row * (NKV * HDIM) + wc * HDIM + 16 * n + l15] = (__bf16)outv;
        }
    }
}

// ---------------------------------------------------------------------------
// Out-projection GEMM 64x160 (r20/r21-proven), grid (M/64, 4).
// ---------------------------------------------------------------------------
__global__ __launch_bounds__(512) void gemm_bf16_n160(
    const __bf16* __restrict__ A, const __bf16* __restrict__ BT,
    float* __restrict__ C, int M, int K, int ldc)
{
    __shared__ __bf16 As[2][2][64][40];    // 20480 B
    __shared__ __bf16 Bs[2][2][160][40];   // 51200 B
    const int BUFA = 64 * 40;
    const int BUFB = 160 * 40;

    const int tid  = threadIdx.x;
    const int wave = tid >> 6;
    const int lane = tid & 63;
    const int wr = wave >> 1, wc = wave & 1;     // 4M x 2N
    const int l15 = lane & 15, lq = lane >> 4;
    const int m0 = blockIdx.x * 64, n0 = blockIdx.y * 160;

    f32x4 acc[5];
    #pragma unroll
    for (int n = 0; n < 5; ++n) acc[n] = (f32x4)0.0f;

    size_t goff[4];
    __bf16* ldst[4];
    int     bstr[4];
    const bool act3 = (tid < 256);
    {
        int r0 = tid >> 3, q0 = tid & 7, h0 = q0 >> 2, s0 = q0 & 3;
        goff[0] = (size_t)(m0 + r0) * K + h0 * 32 + 8 * s0;
        ldst[0] = &As[h0][0][r0][8 * s0];
        bstr[0] = BUFA;
        #pragma unroll
        for (int j = 1; j < 4; ++j) {
            int b  = tid + (j - 1) * 512;
            if (j == 3 && !act3) b = 0;
            int rb = b >> 3, qb = b & 7, hb = qb >> 2, sb = qb & 3;
            goff[j] = (size_t)(n0 + rb) * K + hb * 32 + 8 * sb;
            ldst[j] = &Bs[hb][0][rb][8 * sb];
            bstr[j] = BUFB;
        }
    }
    const __bf16* gsrcs[4] = { A, BT, BT, BT };

    const int nk = K >> 6;

    bf16x8 rg0 = *(const bf16x8*)&gsrcs[0][goff[0]];
    bf16x8 rg1 = *(const bf16x8*)&gsrcs[1][goff[1]];
    bf16x8 rg2 = *(const bf16x8*)&gsrcs[2][goff[2]];
    bf16x8 rg3;
    if (act3) rg3 = *(const bf16x8*)&gsrcs[3][goff[3]];
    *(bf16x8*)ldst[0] = rg0;
    *(bf16x8*)ldst[1] = rg1;
    *(bf16x8*)ldst[2] = rg2;
    if (act3) *(bf16x8*)ldst[3] = rg3;
    __syncthreads();

    for (int ks = 0; ks < nk; ++ks) {
        const int cur = ks & 1;
        if (ks + 1 < nk) {
            const size_t kadv = (size_t)(ks + 1) * 64;
            rg0 = *(const bf16x8*)&gsrcs[0][goff[0] + kadv];
            rg1 = *(const bf16x8*)&gsrcs[1][goff[1] + kadv];
            rg2 = *(const bf16x8*)&gsrcs[2][goff[2] + kadv];
            if (act3) rg3 = *(const bf16x8*)&gsrcs[3][goff[3] + kadv];
        }

        __builtin_amdgcn_s_setprio(1);
        #pragma unroll
        for (int h = 0; h < 2; ++h) {
            bf16x8 af = *(const bf16x8*)&As[h][cur][wr * 16 + l15][8 * lq];
            #pragma unroll
            for (int n = 0; n < 5; ++n) {
                bf16x8 bfr = *(const bf16x8*)&Bs[h][cur][wc * 80 + n * 16 + l15][8 * lq];
                acc[n] = __builtin_amdgcn_mfma_f32_16x16x32_bf16(af, bfr, acc[n], 0, 0, 0);
            }
        }
        __builtin_amdgcn_s_setprio(0);

        if (ks + 1 < nk) {
            *(bf16x8*)(ldst[0] + (cur ^ 1) * bstr[0]) = rg0;
            *(bf16x8*)(ldst[1] + (cur ^ 1) * bstr[1]) = rg1;
            *(bf16x8*)(ldst[2] + (cur ^ 1) * bstr[2]) = rg2;
            if (act3) *(bf16x8*)(ldst[3] + (cur ^ 1) * bstr[3]) = rg3;
        }
        __syncthreads();
    }

    #pragma unroll
    for (int n = 0; n < 5; ++n) {
        const int col = n0 + wc * 80 + n * 16 + l15;
        const int rbase = m0 + wr * 16 + 4 * lq;
        #pragma unroll
        for (int r = 0; r < 4; ++r)
            C[(size_t)(rbase + r) * ldc + col] = acc[n][r];
    }
}

// ---------------------------------------------------------------------------
// GQA-fused MFMA flash attention (r21-proven).
// ---------------------------------------------------------------------------
__global__ __launch_bounds__(512) void flash_attn_mfma(
    const __bf16* __restrict__ qb, const __bf16* __restrict__ kb,
    const __bf16* __restrict__ vtb, __bf16* __restrict__ attnb)
{
    const int bx   = blockIdx.x;
    const int i0   = ((bx & 7) * 16 + (bx >> 3)) * BQG;   // chunked XCD swizzle
    const int kvh  = blockIdx.y;
    const int tid  = threadIdx.x;        // 0..511
    const int w    = tid >> 6;           // 0..7
    const int h    = kvh * 4 + (w >> 1);
    const int wsub = w & 1;
    const int lane = tid & 63;
    const int l15  = lane & 15;
    const int lq   = lane >> 4;

    __shared__ __bf16 Ks[2][BK][KSTR];   // 53248 B
    __shared__ __bf16 Vt[2][HDIM][VSTR]; // 43520 B
    __shared__ __bf16 Pl[128][VSTR];     // 34816 B
    __shared__ __bf16 Ksk[16][KSTR];     //  3328 B (sink K, keys 0..15)
    __shared__ __bf16 Vtk[HDIM][VSTRK];  //  6400 B (sink V, keys 0..31)

    // zero K pad columns 80..95 of BOTH buffers
    {
        int b = tid >> 8, r = (tid >> 1) & 127, c = HDIM + 8 * (tid & 1);
        *(float4*)&Ks[b][r][c] = make_float4(0.f, 0.f, 0.f, 0.f);
    }

    // constant ones-fragment for the l-accumulator
    bf16x8 vones;
    #pragma unroll
    for (int j = 0; j < 8; ++j) vones[j] = (l15 == 0) ? (__bf16)1.0f : (__bf16)0.0f;

    // window staging maps: 1280 chunks of 8 bf16 each (chunk = tid + 512*i)
    int koff[3], voff[3];
    __bf16* ksdst0[3];
    __bf16* vsdst0[3];
    bool act[3];
    #pragma unroll
    for (int i = 0; i < 3; ++i) {
        int c = tid + 512 * i;
        act[i] = (c < 1280);
        int cc = act[i] ? c : 0;
        koff[i] = (cc / 10) * (NKV * HDIM) + 8 * (cc % 10);
        voff[i] = (cc >> 4) * SEQ + 8 * (cc & 15);
        ksdst0[i] = &Ks[0][cc / 10][8 * (cc % 10)];
        vsdst0[i] = &Vt[0][cc >> 4][8 * (cc & 15)];
    }
    const size_t ksbuf = (size_t)BK * KSTR;
    const size_t vsbuf = (size_t)HDIM * VSTR;
    const __bf16* kbase = kb + kvh * HDIM;
    const __bf16* vbase = vtb + (size_t)kvh * HDIM * SEQ;

    // preload Q A-fragments (q-row i0 + 16*wsub + l15)
    bf16x8 qf[3];
    {
        const __bf16* qrow = qb + (size_t)(i0 + 16 * wsub + l15) * HIDDEN + h * HDIM;
        #pragma unroll
        for (int ks = 0; ks < 3; ++ks) {
            int off = 32 * ks + 8 * lq;
            if (off >= HDIM) off = 0;     // dummy: multiplied by zeroed K pad
            qf[ks] = *(const bf16x8*)&qrow[off];
        }
    }

    float m_i = -1e30f, l_i = 0.0f;       // per-lane: q-row i0+16*wsub+l15
    f32x4 o[6];                           // o[5] = P row-sum accumulator
    #pragma unroll
    for (int n = 0; n < 6; ++n) o[n] = (f32x4)0.0f;

    const int w_lo   = i0 - (WINDOW - 1);
    const int w_tile = (w_lo <= 0) ? 0 : (w_lo & ~(BK - 1));
    const int lastt  = (i0 + BQG - 1) & ~(BK - 1);
    const int n_win  = (lastt - w_tile) / BK + 1;
    const bool has_sink = (w_tile > 0);   // sinks disjoint from window

    // ---- prologue: stage tile 0 + sink K/V, one barrier ----
    bf16x8 krg[3], vrg[3];
    #pragma unroll
    for (int i = 0; i < 3; ++i) {
        if (act[i]) {
            krg[i] = *(const bf16x8*)&kbase[(size_t)w_tile * (NKV * HDIM) + koff[i]];
            vrg[i] = *(const bf16x8*)&vbase[(size_t)w_tile + voff[i]];
        }
    }
    if (has_sink) {
        if (tid < 160) {                 // Ksk: 16 rows x 10 chunks
            int r = tid / 10, c8 = tid % 10;
            *(bf16x8*)&Ksk[r][8 * c8] =
                *(const bf16x8*)&kbase[(size_t)r * (NKV * HDIM) + 8 * c8];
        } else if (tid < 192) {          // Ksk pad cols 80..95
            int r = (tid - 160) >> 1, c = HDIM + 8 * (tid & 1);
            *(float4*)&Ksk[r][c] = make_float4(0.f, 0.f, 0.f, 0.f);
        } else if (tid < 512) {          // Vtk: 80 rows x 4 chunks
            int c = tid - 192;           // 0..319
            *(bf16x8*)&Vtk[c >> 2][8 * (c & 3)] =
                *(const bf16x8*)&vbase[(size_t)(c >> 2) * SEQ + 8 * (c & 3)];
        }
    }
    #pragma unroll
    for (int i = 0; i < 3; ++i) {
        if (act[i]) {
            *(bf16x8*)ksdst0[i] = krg[i];
            *(bf16x8*)vsdst0[i] = vrg[i];
        }
    }
    __syncthreads();

    // ---- sink prepass (swapped): keys = 4lq+r, q-row = l15 ----
    if (has_sink) {
        f32x4 sk = (f32x4)0.0f;
        #pragma unroll
        for (int ks = 0; ks < 3; ++ks) {
            bf16x8 kf = *(const bf16x8*)&Ksk[l15][32 * ks + 8 * lq];
            sk = __builtin_amdgcn_mfma_f32_16x16x32_bf16(kf, qf[ks], sk, 0, 0, 0);
        }
        if (lq != 0) {
            #pragma unroll
            for (int r = 0; r < 4; ++r) sk[r] = -1e30f;
        }
        float mx = fmaxf(fmaxf(sk[0], sk[1]), fmaxf(sk[2], sk[3]));
        mx = fmaxf(mx, __shfl_xor(mx, 16));
        mx = fmaxf(mx, __shfl_xor(mx, 32));
        m_i = mx;
        bf16x4 pk;
        float rsum = 0.0f;
        #pragma unroll
        for (int r = 0; r < 4; ++r) {
            float pe = fexp2(sk[r] - m_i);
            pk[r] = (__bf16)pe;
            rsum += pe;
        }
        *(bf16x4*)&Pl[16 * w + l15][4 * lq] = pk;
        bf16x4 zz;
        #pragma unroll
        for (int r = 0; r < 4; ++r) zz[r] = (__bf16)0.0f;
        *(bf16x4*)&Pl[16 * w + l15][16 + 4 * lq] = zz;
        rsum += __shfl_xor(rsum, 16);
        rsum += __shfl_xor(rsum, 32);
        l_i = rsum;
        #pragma unroll
        for (int n = 0; n < 5; ++n) {
            bf16x8 pf = *(const bf16x8*)&Pl[16 * w + l15][8 * lq];
            bf16x8 vf = *(const bf16x8*)&Vtk[16 * n + l15][8 * lq];
            o[n] = __builtin_amdgcn_mfma_f32_16x16x32_bf16(pf, vf, o[n], 0, 0, 0);
        }
    }

    // ---- main loop: window tiles only, 1 barrier/tile ----
    for (int t = 0; t < n_win; ++t) {
        const int cur = t & 1;
        const int j0 = w_tile + t * BK;
        const bool more = (t + 1 < n_win);

        if (more) {
            const int j1 = j0 + BK;
            #pragma unroll
            for (int i = 0; i < 3; ++i) {
                if (act[i]) {
                    krg[i] = *(const bf16x8*)&kbase[(size_t)j1 * (NKV * HDIM) + koff[i]];
                    vrg[i] = *(const bf16x8*)&vbase[(size_t)j1 + voff[i]];
                }
            }
        }

        // ---- S = K Q^T (swapped): 24 MFMA per wave ----
        f32x4 sacc[8];
        #pragma unroll
        for (int n = 0; n < 8; ++n) sacc[n] = (f32x4)0.0f;
        __builtin_amdgcn_s_setprio(1);
        #pragma unroll
        for (int ks = 0; ks < 3; ++ks) {
            #pragma unroll
            for (int n = 0; n < 8; ++n) {
                bf16x8 kf = *(const bf16x8*)&Ks[cur][n * 16 + l15][32 * ks + 8 * lq];
                sacc[n] = __builtin_amdgcn_mfma_f32_16x16x32_bf16(kf, qf[ks], sacc[n], 0, 0, 0);
            }
        }
        __builtin_amdgcn_s_setprio(0);

        // ---- mask: key j = j0+16n+4lq+r, q i = i0+16wsub+l15 ----
        const bool full = (j0 >= i0 - 480) && (j0 <= i0 - 128);
        if (!full) {
            const int i = i0 + 16 * wsub + l15;
            #pragma unroll
            for (int n = 0; n < 8; ++n) {
                #pragma unroll
                for (int r = 0; r < 4; ++r) {
                    int j = j0 + 16 * n + 4 * lq + r;
                    bool allowed = (j <= i) && ((j >= i - (WINDOW - 1)) || (j < SINK));
                    if (!allowed) sacc[n][r] = -1e30f;
                }
            }
        }

        // ---- online softmax (swapped): in-lane max + 2 shfl ----
        {
            float mx = sacc[0][0];
            #pragma unroll
            for (int n = 0; n < 8; ++n) {
                float a = fmaxf(fmaxf(sacc[n][0], sacc[n][1]),
                                fmaxf(sacc[n][2], sacc[n][3]));
                mx = (n == 0) ? a : fmaxf(mx, a);
            }
            mx = fmaxf(mx, __shfl_xor(mx, 16));
            mx = fmaxf(mx, __shfl_xor(mx, 32));

            float alpha_own = 1.0f;
            bool grow = (mx > m_i);
            if (grow) {
                alpha_own = fexp2(m_i - mx);
                m_i = mx;
                l_i *= alpha_own;
            }
            if (__any(grow)) {
                #pragma unroll
                for (int r = 0; r < 4; ++r) {
                    float ar = __shfl(alpha_own, 4 * lq + r);
                    #pragma unroll
                    for (int n = 0; n < 6; ++n) o[n][r] *= ar;
                }
            }
            #pragma unroll
            for (int n = 0; n < 8; ++n) {
                bf16x4 pk;
                #pragma unroll
                for (int r = 0; r < 4; ++r)
                    pk[r] = (__bf16)fexp2(sacc[n][r] - m_i);
                *(bf16x4*)&Pl[16 * w + l15][16 * n + 4 * lq] = pk;
            }
        }

        // ---- O += P V : 20 MFMA + 4 l-accum MFMA per wave ----
        __builtin_amdgcn_s_setprio(1);
        #pragma unroll
        for (int ks = 0; ks < 4; ++ks) {
            bf16x8 pf = *(const bf16x8*)&Pl[16 * w + l15][32 * ks + 8 * lq];
            #pragma unroll
            for (int n = 0; n < 5; ++n) {
                bf16x8 vf = *(const bf16x8*)&Vt[cur][16 * n + l15][32 * ks + 8 * lq];
                o[n] = __builtin_amdgcn_mfma_f32_16x16x32_bf16(pf, vf, o[n], 0, 0, 0);
            }
            o[5] = __builtin_amdgcn_mfma_f32_16x16x32_bf16(pf, vones, o[5], 0, 0, 0);
        }
        __builtin_amdgcn_s_setprio(0);

        // ---- write next tile into the other buffer, then one barrier ----
        if (more) {
            #pragma unroll
            for (int i = 0; i < 3; ++i) {
                if (act[i]) {
                    *(bf16x8*)(ksdst0[i] + (cur ^ 1) * ksbuf) = krg[i];
                    *(bf16x8*)(vsdst0[i] + (cur ^ 1) * vsbuf) = vrg[i];
                }
            }
            __syncthreads();
        }
    }

    // ---- epilogue: l(row 4lq+r) = shfl(l_i) + o[5]@(l15==0) ----
    #pragma unroll
    for (int r = 0; r < 4; ++r) {
        float l_snk = __shfl(l_i, 4 * lq + r);
        float l_pv  = __shfl(o[5][r], lane & 48);
        float inv = 1.0f / (l_snk + l_pv);
        int row = i0 + 16 * wsub + 4 * lq + r;
        #pragma unroll
        for (int n = 0; n < 5; ++n)
            attnb[(size_t)row * HIDDEN + h * HDIM + 16 * n + l15] = (__bf16)(o[n][r] * inv);
    }
}

// ---------------------------------------------------------------------------
extern "C" void kernel_launch(void* const* d_in, const int* in_sizes, int n_in,
                              void* d_out, int out_size, void* d_ws, size_t ws_size,
                              hipStream_t stream)
{
    const float* x    = (const float*)d_in[0];
    const float* cosb = (const float*)d_in[1];
    const float* sinb = (const float*)d_in[2];
    const float* Wq   = (const float*)d_in[3];
    const float* Wk   = (const float*)d_in[4];
    const float* Wv   = (const float*)d_in[5];
    const float* Wo   = (const float*)d_in[6];
    const float* qw   = (const float*)d_in[7];
    const float* kw   = (const float*)d_in[8];
    float* out = (float*)d_out;

    char* ws = (char*)d_ws;
    __bf16* xb    = (__bf16*)ws;                                 // [4096][640] = attnb
    __bf16* qb    = xb   + (size_t)SEQ * HIDDEN;                 // [4096][640]
    __bf16* kb    = qb   + (size_t)SEQ * HIDDEN;                 // [4096][160]
    __bf16* vtb   = kb   + (size_t)SEQ * 160;                    // [2][80][4096]
    __bf16* WqkvT = vtb  + (size_t)2 * HDIM * SEQ;               // [1024][640]
    __bf16* WoT   = WqkvT + (size_t)1024 * HIDDEN;               // [640][640]

    prep_kernel<<<dim3(3560), dim3(256), 0, stream>>>(
        x, Wq, Wk, Wv, Wo, xb, WqkvT, WoT);

    // QKV GEMM with fused rmsnorm+rope (q,k) and V-transpose
    gemm_qkv_fused<<<dim3(SEQ / 64, 6), dim3(512), 0, stream>>>(
        xb, WqkvT, cosb, sinb, qw, kw, qb, kb, vtb, SEQ, HIDDEN);

    flash_attn_mfma<<<dim3(SEQ / BQG, NKV), dim3(512), 0, stream>>>(
        qb, kb, vtb, xb);

    gemm_bf16_n160<<<dim3(SEQ / 64, HIDDEN / 160), dim3(512), 0, stream>>>(
        xb, WoT, out, SEQ, HIDDEN, HIDDEN);
}

// Round 23
// 59.534 us; speedup vs baseline: 1.0045x; 1.0045x over previous
//
#include <hip/hip_runtime.h>
#include <hip/hip_bf16.h>
#include <stdint.h>

#define SEQ     4096
#define HIDDEN  640
#define HDIM    80
#define NH      8
#define NKV     2
#define WINDOW  512
#define SINK    4
#define BQG     32    // flash q-tile (shared by 4 heads)
#define BK      128   // flash key-tile
#define KSTR    104   // Ks row stride (bf16): conflict-free b128 reads
#define VSTR    136   // Vt/Pl row stride (bf16): conflict-free b128 reads
#define VSTRK   40    // Vtk sink row stride

typedef __bf16 bf16x8 __attribute__((ext_vector_type(8)));
typedef __bf16 bf16x4 __attribute__((ext_vector_type(4)));
typedef float  f32x4  __attribute__((ext_vector_type(4)));

__device__ inline __bf16 f2bf(float f) {
    union { float f; uint32_t u; } x; x.f = f;
    uint32_t r = x.u + 0x7FFF + ((x.u >> 16) & 1);   // RNE, no NaN inputs
    union { unsigned short s; __bf16 b; } y; y.s = (unsigned short)(r >> 16);
    return y.b;
}
__device__ inline float bf2f(unsigned short u) {
    union { uint32_t u; float f; } c; c.u = ((uint32_t)u) << 16; return c.f;
}
__device__ inline float fexp2(float x) {
#if __has_builtin(__builtin_amdgcn_exp2f)
    return __builtin_amdgcn_exp2f(x);
#else
    return exp2f(x);
#endif
}

// ---------------------------------------------------------------------------
// Fused prep: x -> bf16 (blocks [0,2560)) + all weight transposes
// (blocks [2560,3560), 32x32 tiles).  (r12-proven)
// ---------------------------------------------------------------------------
__global__ __launch_bounds__(256) void prep_kernel(
    const float* __restrict__ x, const float* __restrict__ Wq,
    const float* __restrict__ Wk, const float* __restrict__ Wv,
    const float* __restrict__ Wo, __bf16* __restrict__ xb,
    __bf16* __restrict__ WqkvT, __bf16* __restrict__ WoT)
{
    const int flat = blockIdx.x;
    const int tid  = threadIdx.x;
    if (flat < 2560) {
        int i = flat * 256 + tid;
        const float4 v = *(const float4*)&x[4 * i];
        xb[4 * i + 0] = f2bf(v.x);
        xb[4 * i + 1] = f2bf(v.y);
        xb[4 * i + 2] = f2bf(v.z);
        xb[4 * i + 3] = f2bf(v.w);
        return;
    }
    const int wf = flat - 2560;
    const float* src;
    __bf16* dstb;
    int idx, tiles_x, N;
    if (wf < 400)      { src = Wq; dstb = WqkvT;             idx = wf;       tiles_x = 20; N = 640; }
    else if (wf < 500) { src = Wk; dstb = WqkvT + 640 * 640; idx = wf - 400; tiles_x = 5;  N = 160; }
    else if (wf < 600) { src = Wv; dstb = WqkvT + 800 * 640; idx = wf - 500; tiles_x = 5;  N = 160; }
    else               { src = Wo; dstb = WoT;               idx = wf - 600; tiles_x = 20; N = 640; }
    const int n0 = (idx % tiles_x) * 32;
    const int k0 = (idx / tiles_x) * 32;

    __shared__ float t[32][33];
    const int tx = tid & 31, ty = tid >> 5;     // 32 x 8
    #pragma unroll
    for (int i = 0; i < 4; ++i) {
        int r = ty + 8 * i;
        t[r][tx] = src[(size_t)(k0 + r) * N + n0 + tx];
    }
    __syncthreads();
    #pragma unroll
    for (int i = 0; i < 4; ++i) {
        int r = ty + 8 * i;
        dstb[(size_t)(n0 + r) * 640 + k0 + tx] = f2bf(t[tx][r]);
    }
}

// ---------------------------------------------------------------------------
// FUSED QKV GEMM + RMSNorm + RoPE + V-transpose (r22-proven). Tile 64x160
// (head-aligned), grid (M/64, 6). 8 waves = 4M x 2N, wave tile 16x80, BK=64.
// ---------------------------------------------------------------------------
__global__ __launch_bounds__(512) void gemm_qkv_fused(
    const __bf16* __restrict__ A, const __bf16* __restrict__ BT,
    const float* __restrict__ cosb, const float* __restrict__ sinb,
    const float* __restrict__ qw, const float* __restrict__ kw,
    __bf16* __restrict__ qb, __bf16* __restrict__ kb,
    __bf16* __restrict__ vtb, int M, int K)
{
    __shared__ __bf16 As[2][2][64][40];    // 20480 B
    __shared__ __bf16 Bs[2][2][160][40];   // 51200 B
    const int BUFA = 64 * 40;
    const int BUFB = 160 * 40;

    const int tid  = threadIdx.x;
    const int wave = tid >> 6;
    const int lane = tid & 63;
    const int wr = wave >> 1, wc = wave & 1;     // 4M x 2N
    const int l15 = lane & 15, lq = lane >> 4;
    const int m0 = blockIdx.x * 64, bn = blockIdx.y, n0 = bn * 160;

    f32x4 acc[5];
    #pragma unroll
    for (int n = 0; n < 5; ++n) acc[n] = (f32x4)0.0f;

    size_t goff[4];
    __bf16* ldst[4];
    int     bstr[4];
    const bool act3 = (tid < 256);
    {
        int r0 = tid >> 3, q0 = tid & 7, h0 = q0 >> 2, s0 = q0 & 3;
        goff[0] = (size_t)(m0 + r0) * K + h0 * 32 + 8 * s0;
        ldst[0] = &As[h0][0][r0][8 * s0];
        bstr[0] = BUFA;
        #pragma unroll
        for (int j = 1; j < 4; ++j) {
            int b  = tid + (j - 1) * 512;
            if (j == 3 && !act3) b = 0;
            int rb = b >> 3, qb_ = b & 7, hb = qb_ >> 2, sb = qb_ & 3;
            goff[j] = (size_t)(n0 + rb) * K + hb * 32 + 8 * sb;
            ldst[j] = &Bs[hb][0][rb][8 * sb];
            bstr[j] = BUFB;
        }
    }
    const __bf16* gsrcs[4] = { A, BT, BT, BT };

    const int nk = K >> 6;

    bf16x8 rg0 = *(const bf16x8*)&gsrcs[0][goff[0]];
    bf16x8 rg1 = *(const bf16x8*)&gsrcs[1][goff[1]];
    bf16x8 rg2 = *(const bf16x8*)&gsrcs[2][goff[2]];
    bf16x8 rg3;
    if (act3) rg3 = *(const bf16x8*)&gsrcs[3][goff[3]];
    *(bf16x8*)ldst[0] = rg0;
    *(bf16x8*)ldst[1] = rg1;
    *(bf16x8*)ldst[2] = rg2;
    if (act3) *(bf16x8*)ldst[3] = rg3;
    __syncthreads();

    for (int ks = 0; ks < nk; ++ks) {
        const int cur = ks & 1;
        if (ks + 1 < nk) {
            const size_t kadv = (size_t)(ks + 1) * 64;
            rg0 = *(const bf16x8*)&gsrcs[0][goff[0] + kadv];
            rg1 = *(const bf16x8*)&gsrcs[1][goff[1] + kadv];
            rg2 = *(const bf16x8*)&gsrcs[2][goff[2] + kadv];
            if (act3) rg3 = *(const bf16x8*)&gsrcs[3][goff[3] + kadv];
        }

        __builtin_amdgcn_s_setprio(1);
        #pragma unroll
        for (int h = 0; h < 2; ++h) {
            bf16x8 af = *(const bf16x8*)&As[h][cur][wr * 16 + l15][8 * lq];
            #pragma unroll
            for (int n = 0; n < 5; ++n) {
                bf16x8 bfr = *(const bf16x8*)&Bs[h][cur][wc * 80 + n * 16 + l15][8 * lq];
                acc[n] = __builtin_amdgcn_mfma_f32_16x16x32_bf16(af, bfr, acc[n], 0, 0, 0);
            }
        }
        __builtin_amdgcn_s_setprio(0);

        if (ks + 1 < nk) {
            *(bf16x8*)(ldst[0] + (cur ^ 1) * bstr[0]) = rg0;
            *(bf16x8*)(ldst[1] + (cur ^ 1) * bstr[1]) = rg1;
            *(bf16x8*)(ldst[2] + (cur ^ 1) * bstr[2]) = rg2;
            if (act3) *(bf16x8*)(ldst[3] + (cur ^ 1) * bstr[3]) = rg3;
        }
        __syncthreads();
    }

    // ---- fused epilogue ----
    if (bn == 5) {
        #pragma unroll
        for (int n = 0; n < 5; ++n) {
            const int dg = wc * 80 + n * 16 + l15;       // 0..159
            #pragma unroll
            for (int r = 0; r < 4; ++r) {
                const int row = m0 + wr * 16 + 4 * lq + r;
                vtb[(size_t)dg * SEQ + row] = f2bf(acc[n][r]);
            }
        }
        return;
    }

    const bool  isq = (bn < 4);
    const int   head = 2 * bn + wc;                      // q: 0..7 ; k: 8,9
    const float outscale = isq ? (0.11180339887498948f * 1.4426950408889634f) : 1.0f;
    const float* wsrc = isq ? qw : kw;
    float wv[5];
    #pragma unroll
    for (int n = 0; n < 5; ++n) wv[n] = wsrc[16 * n + l15];
    const float sgn = (l15 & 1) ? 1.0f : -1.0f;

    #pragma unroll
    for (int r = 0; r < 4; ++r) {
        const int row = m0 + wr * 16 + 4 * lq + r;
        float ss = 0.0f;
        #pragma unroll
        for (int n = 0; n < 5; ++n) ss += acc[n][r] * acc[n][r];
        ss += __shfl_xor(ss, 1);
        ss += __shfl_xor(ss, 2);
        ss += __shfl_xor(ss, 4);
        ss += __shfl_xor(ss, 8);
        const float rms = rsqrtf(ss * (1.0f / HDIM) + 1e-5f);

        #pragma unroll
        for (int n = 0; n < 5; ++n) {
            float v = acc[n][r] * rms * wv[n];
            float p = __shfl_xor(v, 1);
            float c = cosb[(size_t)row * 40 + 8 * n + (l15 >> 1)];
            float s = sinb[(size_t)row * 40 + 8 * n + (l15 >> 1)];
            float outv = (v * c + sgn * p * s) * outscale;
            if (isq)
                qb[(size_t)row * HIDDEN + head * HDIM + 16 * n + l15] = (__bf16)outv;
            else
                kb[(size_t)row * (NKV * HDIM) + wc * HDIM + 16 * n + l15] = (__bf16)outv;
        }
    }
}

// ---------------------------------------------------------------------------
// Out-projection GEMM 64x160 (r20-22-proven), grid (M/64, 4).
// ---------------------------------------------------------------------------
__global__ __launch_bounds__(512) void gemm_bf16_n160(
    const __bf16* __restrict__ A, const __bf16* __restrict__ BT,
    float* __restrict__ C, int M, int K, int ldc)
{
    __shared__ __bf16 As[2][2][64][40];    // 20480 B
    __shared__ __bf16 Bs[2][2][160][40];   // 51200 B
    const int BUFA = 64 * 40;
    const int BUFB = 160 * 40;

    const int tid  = threadIdx.x;
    const int wave = tid >> 6;
    const int lane = tid & 63;
    const int wr = wave >> 1, wc = wave & 1;     // 4M x 2N
    const int l15 = lane & 15, lq = lane >> 4;
    const int m0 = blockIdx.x * 64, n0 = blockIdx.y * 160;

    f32x4 acc[5];
    #pragma unroll
    for (int n = 0; n < 5; ++n) acc[n] = (f32x4)0.0f;

    size_t goff[4];
    __bf16* ldst[4];
    int     bstr[4];
    const bool act3 = (tid < 256);
    {
        int r0 = tid >> 3, q0 = tid & 7, h0 = q0 >> 2, s0 = q0 & 3;
        goff[0] = (size_t)(m0 + r0) * K + h0 * 32 + 8 * s0;
        ldst[0] = &As[h0][0][r0][8 * s0];
        bstr[0] = BUFA;
        #pragma unroll
        for (int j = 1; j < 4; ++j) {
            int b  = tid + (j - 1) * 512;
            if (j == 3 && !act3) b = 0;
            int rb = b >> 3, qb = b & 7, hb = qb >> 2, sb = qb & 3;
            goff[j] = (size_t)(n0 + rb) * K + hb * 32 + 8 * sb;
            ldst[j] = &Bs[hb][0][rb][8 * sb];
            bstr[j] = BUFB;
        }
    }
    const __bf16* gsrcs[4] = { A, BT, BT, BT };

    const int nk = K >> 6;

    bf16x8 rg0 = *(const bf16x8*)&gsrcs[0][goff[0]];
    bf16x8 rg1 = *(const bf16x8*)&gsrcs[1][goff[1]];
    bf16x8 rg2 = *(const bf16x8*)&gsrcs[2][goff[2]];
    bf16x8 rg3;
    if (act3) rg3 = *(const bf16x8*)&gsrcs[3][goff[3]];
    *(bf16x8*)ldst[0] = rg0;
    *(bf16x8*)ldst[1] = rg1;
    *(bf16x8*)ldst[2] = rg2;
    if (act3) *(bf16x8*)ldst[3] = rg3;
    __syncthreads();

    for (int ks = 0; ks < nk; ++ks) {
        const int cur = ks & 1;
        if (ks + 1 < nk) {
            const size_t kadv = (size_t)(ks + 1) * 64;
            rg0 = *(const bf16x8*)&gsrcs[0][goff[0] + kadv];
            rg1 = *(const bf16x8*)&gsrcs[1][goff[1] + kadv];
            rg2 = *(const bf16x8*)&gsrcs[2][goff[2] + kadv];
            if (act3) rg3 = *(const bf16x8*)&gsrcs[3][goff[3] + kadv];
        }

        __builtin_amdgcn_s_setprio(1);
        #pragma unroll
        for (int h = 0; h < 2; ++h) {
            bf16x8 af = *(const bf16x8*)&As[h][cur][wr * 16 + l15][8 * lq];
            #pragma unroll
            for (int n = 0; n < 5; ++n) {
                bf16x8 bfr = *(const bf16x8*)&Bs[h][cur][wc * 80 + n * 16 + l15][8 * lq];
                acc[n] = __builtin_amdgcn_mfma_f32_16x16x32_bf16(af, bfr, acc[n], 0, 0, 0);
            }
        }
        __builtin_amdgcn_s_setprio(0);

        if (ks + 1 < nk) {
            *(bf16x8*)(ldst[0] + (cur ^ 1) * bstr[0]) = rg0;
            *(bf16x8*)(ldst[1] + (cur ^ 1) * bstr[1]) = rg1;
            *(bf16x8*)(ldst[2] + (cur ^ 1) * bstr[2]) = rg2;
            if (act3) *(bf16x8*)(ldst[3] + (cur ^ 1) * bstr[3]) = rg3;
        }
        __syncthreads();
    }

    #pragma unroll
    for (int n = 0; n < 5; ++n) {
        const int col = n0 + wc * 80 + n * 16 + l15;
        const int rbase = m0 + wr * 16 + 4 * lq;
        #pragma unroll
        for (int r = 0; r < 4; ++r)
            C[(size_t)(rbase + r) * ldc + col] = acc[n][r];
    }
}

// ---------------------------------------------------------------------------
// GQA-fused MFMA flash attention (r22-proven) + T13 defer-max (THR=8 in the
// exp2 domain): rescale only when the tile max exceeds the running max by
// more than 8 -> P bounded by 2^8 (bf16-safe), the o-rescale pass becomes
// cold after the first tiles.
// ---------------------------------------------------------------------------
__global__ __launch_bounds__(512) void flash_attn_mfma(
    const __bf16* __restrict__ qb, const __bf16* __restrict__ kb,
    const __bf16* __restrict__ vtb, __bf16* __restrict__ attnb)
{
    const int bx   = blockIdx.x;
    const int i0   = ((bx & 7) * 16 + (bx >> 3)) * BQG;   // chunked XCD swizzle
    const int kvh  = blockIdx.y;
    const int tid  = threadIdx.x;        // 0..511
    const int w    = tid >> 6;           // 0..7
    const int h    = kvh * 4 + (w >> 1);
    const int wsub = w & 1;
    const int lane = tid & 63;
    const int l15  = lane & 15;
    const int lq   = lane >> 4;

    __shared__ __bf16 Ks[2][BK][KSTR];   // 53248 B
    __shared__ __bf16 Vt[2][HDIM][VSTR]; // 43520 B
    __shared__ __bf16 Pl[128][VSTR];     // 34816 B
    __shared__ __bf16 Ksk[16][KSTR];     //  3328 B (sink K, keys 0..15)
    __shared__ __bf16 Vtk[HDIM][VSTRK];  //  6400 B (sink V, keys 0..31)

    // zero K pad columns 80..95 of BOTH buffers
    {
        int b = tid >> 8, r = (tid >> 1) & 127, c = HDIM + 8 * (tid & 1);
        *(float4*)&Ks[b][r][c] = make_float4(0.f, 0.f, 0.f, 0.f);
    }

    // constant ones-fragment for the l-accumulator
    bf16x8 vones;
    #pragma unroll
    for (int j = 0; j < 8; ++j) vones[j] = (l15 == 0) ? (__bf16)1.0f : (__bf16)0.0f;

    // window staging maps: 1280 chunks of 8 bf16 each (chunk = tid + 512*i)
    int koff[3], voff[3];
    __bf16* ksdst0[3];
    __bf16* vsdst0[3];
    bool act[3];
    #pragma unroll
    for (int i = 0; i < 3; ++i) {
        int c = tid + 512 * i;
        act[i] = (c < 1280);
        int cc = act[i] ? c : 0;
        koff[i] = (cc / 10) * (NKV * HDIM) + 8 * (cc % 10);
        voff[i] = (cc >> 4) * SEQ + 8 * (cc & 15);
        ksdst0[i] = &Ks[0][cc / 10][8 * (cc % 10)];
        vsdst0[i] = &Vt[0][cc >> 4][8 * (cc & 15)];
    }
    const size_t ksbuf = (size_t)BK * KSTR;
    const size_t vsbuf = (size_t)HDIM * VSTR;
    const __bf16* kbase = kb + kvh * HDIM;
    const __bf16* vbase = vtb + (size_t)kvh * HDIM * SEQ;

    // preload Q A-fragments (q-row i0 + 16*wsub + l15)
    bf16x8 qf[3];
    {
        const __bf16* qrow = qb + (size_t)(i0 + 16 * wsub + l15) * HIDDEN + h * HDIM;
        #pragma unroll
        for (int ks = 0; ks < 3; ++ks) {
            int off = 32 * ks + 8 * lq;
            if (off >= HDIM) off = 0;     // dummy: multiplied by zeroed K pad
            qf[ks] = *(const bf16x8*)&qrow[off];
        }
    }

    float m_i = -1e30f, l_i = 0.0f;       // per-lane: q-row i0+16*wsub+l15
    f32x4 o[6];                           // o[5] = P row-sum accumulator
    #pragma unroll
    for (int n = 0; n < 6; ++n) o[n] = (f32x4)0.0f;

    const int w_lo   = i0 - (WINDOW - 1);
    const int w_tile = (w_lo <= 0) ? 0 : (w_lo & ~(BK - 1));
    const int lastt  = (i0 + BQG - 1) & ~(BK - 1);
    const int n_win  = (lastt - w_tile) / BK + 1;
    const bool has_sink = (w_tile > 0);   // sinks disjoint from window

    // ---- prologue: stage tile 0 + sink K/V, one barrier ----
    bf16x8 krg[3], vrg[3];
    #pragma unroll
    for (int i = 0; i < 3; ++i) {
        if (act[i]) {
            krg[i] = *(const bf16x8*)&kbase[(size_t)w_tile * (NKV * HDIM) + koff[i]];
            vrg[i] = *(const bf16x8*)&vbase[(size_t)w_tile + voff[i]];
        }
    }
    if (has_sink) {
        if (tid < 160) {                 // Ksk: 16 rows x 10 chunks
            int r = tid / 10, c8 = tid % 10;
            *(bf16x8*)&Ksk[r][8 * c8] =
                *(const bf16x8*)&kbase[(size_t)r * (NKV * HDIM) + 8 * c8];
        } else if (tid < 192) {          // Ksk pad cols 80..95
            int r = (tid - 160) >> 1, c = HDIM + 8 * (tid & 1);
            *(float4*)&Ksk[r][c] = make_float4(0.f, 0.f, 0.f, 0.f);
        } else if (tid < 512) {          // Vtk: 80 rows x 4 chunks
            int c = tid - 192;           // 0..319
            *(bf16x8*)&Vtk[c >> 2][8 * (c & 3)] =
                *(const bf16x8*)&vbase[(size_t)(c >> 2) * SEQ + 8 * (c & 3)];
        }
    }
    #pragma unroll
    for (int i = 0; i < 3; ++i) {
        if (act[i]) {
            *(bf16x8*)ksdst0[i] = krg[i];
            *(bf16x8*)vsdst0[i] = vrg[i];
        }
    }
    __syncthreads();

    // ---- sink prepass (swapped): keys = 4lq+r, q-row = l15 ----
    if (has_sink) {
        f32x4 sk = (f32x4)0.0f;
        #pragma unroll
        for (int ks = 0; ks < 3; ++ks) {
            bf16x8 kf = *(const bf16x8*)&Ksk[l15][32 * ks + 8 * lq];
            sk = __builtin_amdgcn_mfma_f32_16x16x32_bf16(kf, qf[ks], sk, 0, 0, 0);
        }
        if (lq != 0) {
            #pragma unroll
            for (int r = 0; r < 4; ++r) sk[r] = -1e30f;
        }
        float mx = fmaxf(fmaxf(sk[0], sk[1]), fmaxf(sk[2], sk[3]));
        mx = fmaxf(mx, __shfl_xor(mx, 16));
        mx = fmaxf(mx, __shfl_xor(mx, 32));
        m_i = mx;
        bf16x4 pk;
        float rsum = 0.0f;
        #pragma unroll
        for (int r = 0; r < 4; ++r) {
            float pe = fexp2(sk[r] - m_i);
            pk[r] = (__bf16)pe;
            rsum += pe;
        }
        *(bf16x4*)&Pl[16 * w + l15][4 * lq] = pk;
        bf16x4 zz;
        #pragma unroll
        for (int r = 0; r < 4; ++r) zz[r] = (__bf16)0.0f;
        *(bf16x4*)&Pl[16 * w + l15][16 + 4 * lq] = zz;
        rsum += __shfl_xor(rsum, 16);
        rsum += __shfl_xor(rsum, 32);
        l_i = rsum;
        #pragma unroll
        for (int n = 0; n < 5; ++n) {
            bf16x8 pf = *(const bf16x8*)&Pl[16 * w + l15][8 * lq];
            bf16x8 vf = *(const bf16x8*)&Vtk[16 * n + l15][8 * lq];
            o[n] = __builtin_amdgcn_mfma_f32_16x16x32_bf16(pf, vf, o[n], 0, 0, 0);
        }
    }

    // ---- main loop: window tiles only, 1 barrier/tile ----
    for (int t = 0; t < n_win; ++t) {
        const int cur = t & 1;
        const int j0 = w_tile + t * BK;
        const bool more = (t + 1 < n_win);

        if (more) {
            const int j1 = j0 + BK;
            #pragma unroll
            for (int i = 0; i < 3; ++i) {
                if (act[i]) {
                    krg[i] = *(const bf16x8*)&kbase[(size_t)j1 * (NKV * HDIM) + koff[i]];
                    vrg[i] = *(const bf16x8*)&vbase[(size_t)j1 + voff[i]];
                }
            }
        }

        // ---- S = K Q^T (swapped): 24 MFMA per wave ----
        f32x4 sacc[8];
        #pragma unroll
        for (int n = 0; n < 8; ++n) sacc[n] = (f32x4)0.0f;
        __builtin_amdgcn_s_setprio(1);
        #pragma unroll
        for (int ks = 0; ks < 3; ++ks) {
            #pragma unroll
            for (int n = 0; n < 8; ++n) {
                bf16x8 kf = *(const bf16x8*)&Ks[cur][n * 16 + l15][32 * ks + 8 * lq];
                sacc[n] = __builtin_amdgcn_mfma_f32_16x16x32_bf16(kf, qf[ks], sacc[n], 0, 0, 0);
            }
        }
        __builtin_amdgcn_s_setprio(0);

        // ---- mask: key j = j0+16n+4lq+r, q i = i0+16wsub+l15 ----
        const bool full = (j0 >= i0 - 480) && (j0 <= i0 - 128);
        if (!full) {
            const int i = i0 + 16 * wsub + l15;
            #pragma unroll
            for (int n = 0; n < 8; ++n) {
                #pragma unroll
                for (int r = 0; r < 4; ++r) {
                    int j = j0 + 16 * n + 4 * lq + r;
                    bool allowed = (j <= i) && ((j >= i - (WINDOW - 1)) || (j < SINK));
                    if (!allowed) sacc[n][r] = -1e30f;
                }
            }
        }

        // ---- online softmax: defer-max (THR=8), in-lane max + 2 shfl ----
        {
            float mx = sacc[0][0];
            #pragma unroll
            for (int n = 0; n < 8; ++n) {
                float a = fmaxf(fmaxf(sacc[n][0], sacc[n][1]),
                                fmaxf(sacc[n][2], sacc[n][3]));
                mx = (n == 0) ? a : fmaxf(mx, a);
            }
            mx = fmaxf(mx, __shfl_xor(mx, 16));
            mx = fmaxf(mx, __shfl_xor(mx, 32));

            float alpha_own = 1.0f;
            bool grow = (mx > m_i + 8.0f);   // T13: tolerate P up to 2^8
            if (grow) {
                alpha_own = fexp2(m_i - mx);
                m_i = mx;
                l_i *= alpha_own;
            }
            if (__any(grow)) {
                #pragma unroll
                for (int r = 0; r < 4; ++r) {
                    float ar = __shfl(alpha_own, 4 * lq + r);
                    #pragma unroll
                    for (int n = 0; n < 6; ++n) o[n][r] *= ar;
                }
            }
            #pragma unroll
            for (int n = 0; n < 8; ++n) {
                bf16x4 pk;
                #pragma unroll
                for (int r = 0; r < 4; ++r)
                    pk[r] = (__bf16)fexp2(sacc[n][r] - m_i);
                *(bf16x4*)&Pl[16 * w + l15][16 * n + 4 * lq] = pk;
            }
        }

        // ---- O += P V : 20 MFMA + 4 l-accum MFMA per wave ----
        __builtin_amdgcn_s_setprio(1);
        #pragma unroll
        for (int ks = 0; ks < 4; ++ks) {
            bf16x8 pf = *(const bf16x8*)&Pl[16 * w + l15][32 * ks + 8 * lq];
            #pragma unroll
            for (int n = 0; n < 5; ++n) {
                bf16x8 vf = *(const bf16x8*)&Vt[cur][16 * n + l15][32 * ks + 8 * lq];
                o[n] = __builtin_amdgcn_mfma_f32_16x16x32_bf16(pf, vf, o[n], 0, 0, 0);
            }
            o[5] = __builtin_amdgcn_mfma_f32_16x16x32_bf16(pf, vones, o[5], 0, 0, 0);
        }
        __builtin_amdgcn_s_setprio(0);

        // ---- write next tile into the other buffer, then one barrier ----
        if (more) {
            #pragma unroll
            for (int i = 0; i < 3; ++i) {
                if (act[i]) {
                    *(bf16x8*)(ksdst0[i] + (cur ^ 1) * ksbuf) = krg[i];
                    *(bf16x8*)(vsdst0[i] + (cur ^ 1) * vsbuf) = vrg[i];
                }
            }
            __syncthreads();
        }
    }

    // ---- epilogue: l(row 4lq+r) = shfl(l_i) + o[5]@(l15==0) ----
    #pragma unroll
    for (int r = 0; r < 4; ++r) {
        float l_snk = __shfl(l_i, 4 * lq + r);
        float l_pv  = __shfl(o[5][r], lane & 48);
        float inv = 1.0f / (l_snk + l_pv);
        int row = i0 + 16 * wsub + 4 * lq + r;
        #pragma unroll
        for (int n = 0; n < 5; ++n)
            attnb[(size_t)row * HIDDEN + h * HDIM + 16 * n + l15] = (__bf16)(o[n][r] * inv);
    }
}

// ---------------------------------------------------------------------------
extern "C" void kernel_launch(void* const* d_in, const int* in_sizes, int n_in,
                              void* d_out, int out_size, void* d_ws, size_t ws_size,
                              hipStream_t stream)
{
    const float* x    = (const float*)d_in[0];
    const float* cosb = (const float*)d_in[1];
    const float* sinb = (const float*)d_in[2];
    const float* Wq   = (const float*)d_in[3];
    const float* Wk   = (const float*)d_in[4];
    const float* Wv   = (const float*)d_in[5];
    const float* Wo   = (const float*)d_in[6];
    const float* qw   = (const float*)d_in[7];
    const float* kw   = (const float*)d_in[8];
    float* out = (float*)d_out;

    char* ws = (char*)d_ws;
    __bf16* xb    = (__bf16*)ws;                                 // [4096][640] = attnb
    __bf16* qb    = xb   + (size_t)SEQ * HIDDEN;                 // [4096][640]
    __bf16* kb    = qb   + (size_t)SEQ * HIDDEN;                 // [4096][160]
    __bf16* vtb   = kb   + (size_t)SEQ * 160;                    // [2][80][4096]
    __bf16* WqkvT = vtb  + (size_t)2 * HDIM * SEQ;               // [1024][640]
    __bf16* WoT   = WqkvT + (size_t)1024 * HIDDEN;               // [640][640]

    prep_kernel<<<dim3(3560), dim3(256), 0, stream>>>(
        x, Wq, Wk, Wv, Wo, xb, WqkvT, WoT);

    gemm_qkv_fused<<<dim3(SEQ / 64, 6), dim3(512), 0, stream>>>(
        xb, WqkvT, cosb, sinb, qw, kw, qb, kb, vtb, SEQ, HIDDEN);

    flash_attn_mfma<<<dim3(SEQ / BQG, NKV), dim3(512), 0, stream>>>(
        qb, kb, vtb, xb);

    gemm_bf16_n160<<<dim3(SEQ / 64, HIDDEN / 160), dim3(512), 0, stream>>>(
        xb, WoT, out, SEQ, HIDDEN, HIDDEN);
}